// Round 1
// baseline (97.426 us; speedup 1.0000x reference)
//
#include <hip/hip_runtime.h>
#include <math.h>

#define SEQ 1024
#define DIN 4
#define NH  32
#define DV  8

// One thread per (b, h, s) query row. Block = 256 threads covers 256 rows of
// one (b,h); grid = B*NH*(SEQ/256) = 512 blocks.
// scores[s,t] = x_s^T M x_t with M = Wq Wk^T / sqrt(8)  (4x4 per head)
// ctx[s,:]    = (sum_t softmax_w * x_t) @ Wv            (project at the end)
__global__ __launch_bounds__(256, 2) void mha_kernel(
    const float* __restrict__ x,    // [B, SEQ, 4]
    const float* __restrict__ Wq,   // [NH, 4, 8]
    const float* __restrict__ Wk,   // [NH, 4, 8]
    const float* __restrict__ Wv,   // [NH, 4, 8]
    float* __restrict__ out)        // [B, SEQ, NH*DV]
{
    const int blk   = blockIdx.x;
    const int chunk = blk & 3;          // SEQ/256 = 4 chunks
    const int h     = (blk >> 2) & 31;
    const int b     = blk >> 7;

    __shared__ float4 xs[SEQ];          // 16 KB: x for this batch
    const float4* xg = (const float4*)(x + (size_t)b * SEQ * DIN);
    for (int i = threadIdx.x; i < SEQ; i += 256)
        xs[i] = xg[i];

    // Per-thread compute of M = Wq[h] Wk[h]^T / sqrt(8). 128 FMAs, negligible;
    // weights are tiny and L1/L2-cached.
    const float* wq = Wq + h * DIN * 8;
    const float* wk = Wk + h * DIN * 8;
    const float scale = 0.35355339059327373f; // 1/sqrt(8)
    float M[4][4];
#pragma unroll
    for (int i = 0; i < 4; ++i) {
#pragma unroll
        for (int j = 0; j < 4; ++j) {
            float acc = 0.f;
#pragma unroll
            for (int k = 0; k < 8; ++k)
                acc += wq[i * 8 + k] * wk[j * 8 + k];
            M[i][j] = acc * scale;
        }
    }

    __syncthreads();

    const int s = chunk * 256 + threadIdx.x;
    const float4 xq = xs[s];
    // y = x_s^T M  (4-vector); score(t) = dot(y, x_t)
    const float y0 = xq.x * M[0][0] + xq.y * M[1][0] + xq.z * M[2][0] + xq.w * M[3][0];
    const float y1 = xq.x * M[0][1] + xq.y * M[1][1] + xq.z * M[2][1] + xq.w * M[3][1];
    const float y2 = xq.x * M[0][2] + xq.y * M[1][2] + xq.z * M[2][2] + xq.w * M[3][2];
    const float y3 = xq.x * M[0][3] + xq.y * M[1][3] + xq.z * M[2][3] + xq.w * M[3][3];

    // Single-pass online softmax, unrolled x4 (one rescale per group of 4).
    float m = -INFINITY;
    float l = 0.f;
    float z0 = 0.f, z1 = 0.f, z2 = 0.f, z3 = 0.f;

    for (int t = 0; t < SEQ; t += 4) {
        float4 xt0 = xs[t + 0];
        float4 xt1 = xs[t + 1];
        float4 xt2 = xs[t + 2];
        float4 xt3 = xs[t + 3];
        float s0 = y0 * xt0.x + y1 * xt0.y + y2 * xt0.z + y3 * xt0.w;
        float s1 = y0 * xt1.x + y1 * xt1.y + y2 * xt1.z + y3 * xt1.w;
        float s2 = y0 * xt2.x + y1 * xt2.y + y2 * xt2.z + y3 * xt2.w;
        float s3 = y0 * xt3.x + y1 * xt3.y + y2 * xt3.z + y3 * xt3.w;

        float gmax = fmaxf(fmaxf(s0, s1), fmaxf(s2, s3));
        float mn   = fmaxf(m, gmax);
        float c    = __expf(m - mn);     // exp(-inf) = 0 handles first iter
        float e0 = __expf(s0 - mn);
        float e1 = __expf(s1 - mn);
        float e2 = __expf(s2 - mn);
        float e3 = __expf(s3 - mn);

        l  = l * c + (e0 + e1) + (e2 + e3);
        z0 = z0 * c + e0 * xt0.x + e1 * xt1.x + e2 * xt2.x + e3 * xt3.x;
        z1 = z1 * c + e0 * xt0.y + e1 * xt1.y + e2 * xt2.y + e3 * xt3.y;
        z2 = z2 * c + e0 * xt0.z + e1 * xt1.z + e2 * xt2.z + e3 * xt3.z;
        z3 = z3 * c + e0 * xt0.w + e1 * xt1.w + e2 * xt2.w + e3 * xt3.w;
        m = mn;
    }

    const float inv = 1.f / l;
    const float* wv = Wv + h * DIN * 8;
    float o[8];
#pragma unroll
    for (int j = 0; j < 8; ++j) {
        o[j] = inv * (z0 * wv[0 * 8 + j] + z1 * wv[1 * 8 + j] +
                      z2 * wv[2 * 8 + j] + z3 * wv[3 * 8 + j]);
    }

    float4* op = (float4*)(out + ((size_t)b * SEQ + s) * (NH * DV) + h * DV);
    op[0] = make_float4(o[0], o[1], o[2], o[3]);
    op[1] = make_float4(o[4], o[5], o[6], o[7]);
}

extern "C" void kernel_launch(void* const* d_in, const int* in_sizes, int n_in,
                              void* d_out, int out_size, void* d_ws, size_t ws_size,
                              hipStream_t stream) {
    const float* x  = (const float*)d_in[0];
    const float* Wq = (const float*)d_in[1];
    const float* Wk = (const float*)d_in[2];
    const float* Wv = (const float*)d_in[3];
    float* out = (float*)d_out;

    const int B = in_sizes[0] / (SEQ * DIN);       // 4
    dim3 grid(B * NH * (SEQ / 256));
    dim3 block(256);
    hipLaunchKernelGGL(mha_kernel, grid, block, 0, stream, x, Wq, Wk, Wv, out);
}

// Round 2
// 41.727 us; speedup vs baseline: 2.3348x; 2.3348x over previous
//
#include <hip/hip_runtime.h>
#include <math.h>

#define SEQ   1024
#define DIN   4
#define NH    32
#define DV    8
#define ROWS  64      // query rows per block
#define NSPLIT 4      // t-range splits, one per wave

__device__ inline float fast_exp2(float x) {
#if __has_builtin(__builtin_amdgcn_exp2f)
    return __builtin_amdgcn_exp2f(x);
#else
    return __expf(x * 0.6931471805599453f);
#endif
}

// Block = 256 threads = 4 waves. wave w handles t-range [w*256, w*256+256)
// for 64 query rows (lane = row). Partials combined via LDS (aliased onto xs).
// scores2[s,t] = x_s^T M' x_t  with  M' = Wq Wk^T * (1/sqrt(8)) * log2(e)
// weight = exp2(scores2 - mub2), mub2 = sum_j |y_j| * max_t |x_t[j]|  (>= row max)
__global__ __launch_bounds__(256, 8) void mha_kernel(
    const float* __restrict__ x,    // [B, SEQ, 4]
    const float* __restrict__ Wq,   // [NH, 4, 8]
    const float* __restrict__ Wk,   // [NH, 4, 8]
    const float* __restrict__ Wv,   // [NH, 4, 8]
    float* __restrict__ out)        // [B, SEQ, NH*DV]
{
    const int bid  = blockIdx.x;
    const int rc   = bid & 15;          // row chunk (SEQ/ROWS = 16)
    const int h    = (bid >> 4) & 31;
    const int b    = bid >> 9;

    const int tid  = threadIdx.x;
    const int lane = tid & 63;
    const int wave = tid >> 6;          // split index

    __shared__ float4 xs[SEQ];          // 16 KB
    __shared__ float4 amw[NSPLIT];      // per-wave |x| max partials

    // ---- stage x[b] into LDS, tracking per-component |x| max ----
    const float4* xg = (const float4*)(x + (size_t)b * SEQ * DIN);
    float4 am = make_float4(0.f, 0.f, 0.f, 0.f);
    for (int i = tid; i < SEQ; i += 256) {
        float4 v = xg[i];
        xs[i] = v;
        am.x = fmaxf(am.x, fabsf(v.x));
        am.y = fmaxf(am.y, fabsf(v.y));
        am.z = fmaxf(am.z, fabsf(v.z));
        am.w = fmaxf(am.w, fabsf(v.w));
    }
#pragma unroll
    for (int off = 32; off; off >>= 1) {
        am.x = fmaxf(am.x, __shfl_xor(am.x, off));
        am.y = fmaxf(am.y, __shfl_xor(am.y, off));
        am.z = fmaxf(am.z, __shfl_xor(am.z, off));
        am.w = fmaxf(am.w, __shfl_xor(am.w, off));
    }
    if (lane == 0) amw[wave] = am;

    // ---- per-thread M' = Wq Wk^T * scale * log2e (prologue, tiny) ----
    const float* wq = Wq + h * DIN * 8;
    const float* wk = Wk + h * DIN * 8;
    const float cs = 0.35355339059327373f * 1.4426950408889634f;
    float M[4][4];
#pragma unroll
    for (int i = 0; i < 4; ++i)
#pragma unroll
        for (int j = 0; j < 4; ++j) {
            float acc = 0.f;
#pragma unroll
            for (int k = 0; k < 8; ++k)
                acc += wq[i * 8 + k] * wk[j * 8 + k];
            M[i][j] = acc * cs;
        }

    __syncthreads();

    float4 A = amw[0];
    A.x = fmaxf(fmaxf(A.x, amw[1].x), fmaxf(amw[2].x, amw[3].x));
    A.y = fmaxf(fmaxf(A.y, amw[1].y), fmaxf(amw[2].y, amw[3].y));
    A.z = fmaxf(fmaxf(A.z, amw[1].z), fmaxf(amw[2].z, amw[3].z));
    A.w = fmaxf(fmaxf(A.w, amw[1].w), fmaxf(amw[2].w, amw[3].w));

    const int s = rc * ROWS + lane;
    const float4 xq = xs[s];
    const float y0 = xq.x * M[0][0] + xq.y * M[1][0] + xq.z * M[2][0] + xq.w * M[3][0];
    const float y1 = xq.x * M[0][1] + xq.y * M[1][1] + xq.z * M[2][1] + xq.w * M[3][1];
    const float y2 = xq.x * M[0][2] + xq.y * M[1][2] + xq.z * M[2][2] + xq.w * M[3][2];
    const float y3 = xq.x * M[0][3] + xq.y * M[1][3] + xq.z * M[2][3] + xq.w * M[3][3];
    // guaranteed upper bound of this row's scores (exp2 arg always <= 0)
    const float neg = -(fabsf(y0) * A.x + fabsf(y1) * A.y +
                        fabsf(y2) * A.z + fabsf(y3) * A.w);

    float la = 0.f, lb = 0.f;
    float z0 = 0.f, z1 = 0.f, z2 = 0.f, z3 = 0.f;

    const int t0 = wave * (SEQ / NSPLIT);
    for (int t = t0; t < t0 + SEQ / NSPLIT; t += 4) {
        float4 xt0 = xs[t + 0];
        float4 xt1 = xs[t + 1];
        float4 xt2 = xs[t + 2];
        float4 xt3 = xs[t + 3];
        float s0 = fmaf(y0, xt0.x, fmaf(y1, xt0.y, fmaf(y2, xt0.z, fmaf(y3, xt0.w, neg))));
        float s1 = fmaf(y0, xt1.x, fmaf(y1, xt1.y, fmaf(y2, xt1.z, fmaf(y3, xt1.w, neg))));
        float s2 = fmaf(y0, xt2.x, fmaf(y1, xt2.y, fmaf(y2, xt2.z, fmaf(y3, xt2.w, neg))));
        float s3 = fmaf(y0, xt3.x, fmaf(y1, xt3.y, fmaf(y2, xt3.z, fmaf(y3, xt3.w, neg))));
        float e0 = fast_exp2(s0);
        float e1 = fast_exp2(s1);
        float e2 = fast_exp2(s2);
        float e3 = fast_exp2(s3);
        la += e0 + e1;
        lb += e2 + e3;
        z0 = fmaf(e0, xt0.x, fmaf(e1, xt1.x, fmaf(e2, xt2.x, fmaf(e3, xt3.x, z0))));
        z1 = fmaf(e0, xt0.y, fmaf(e1, xt1.y, fmaf(e2, xt2.y, fmaf(e3, xt3.y, z1))));
        z2 = fmaf(e0, xt0.z, fmaf(e1, xt1.z, fmaf(e2, xt2.z, fmaf(e3, xt3.z, z2))));
        z3 = fmaf(e0, xt0.w, fmaf(e1, xt1.w, fmaf(e2, xt2.w, fmaf(e3, xt3.w, z3))));
    }

    // ---- combine the 4 splits via LDS (alias onto xs, done reading it) ----
    __syncthreads();
    float*  pl = (float*)xs;                       // [NSPLIT*ROWS]
    float4* pz = (float4*)(pl + NSPLIT * ROWS);    // [NSPLIT*ROWS]
    pl[wave * ROWS + lane] = la + lb;
    pz[wave * ROWS + lane] = make_float4(z0, z1, z2, z3);
    __syncthreads();

    if (tid < 2 * ROWS) {
        const int row  = tid >> 1;
        const int half = tid & 1;
        float l = pl[row] + pl[ROWS + row] + pl[2 * ROWS + row] + pl[3 * ROWS + row];
        float4 za = pz[row], zb = pz[ROWS + row], zc = pz[2 * ROWS + row], zd = pz[3 * ROWS + row];
        float Z0 = za.x + zb.x + zc.x + zd.x;
        float Z1 = za.y + zb.y + zc.y + zd.y;
        float Z2 = za.z + zb.z + zc.z + zd.z;
        float Z3 = za.w + zb.w + zc.w + zd.w;
        float inv = 1.f / l;
        const float* wv = Wv + h * DIN * 8 + half * 4;
        float4 o;
        o.x = inv * (Z0 * wv[0 * 8 + 0] + Z1 * wv[1 * 8 + 0] + Z2 * wv[2 * 8 + 0] + Z3 * wv[3 * 8 + 0]);
        o.y = inv * (Z0 * wv[0 * 8 + 1] + Z1 * wv[1 * 8 + 1] + Z2 * wv[2 * 8 + 1] + Z3 * wv[3 * 8 + 1]);
        o.z = inv * (Z0 * wv[0 * 8 + 2] + Z1 * wv[1 * 8 + 2] + Z2 * wv[2 * 8 + 2] + Z3 * wv[3 * 8 + 2]);
        o.w = inv * (Z0 * wv[0 * 8 + 3] + Z1 * wv[1 * 8 + 3] + Z2 * wv[2 * 8 + 3] + Z3 * wv[3 * 8 + 3]);
        float4* op = (float4*)(out + ((size_t)(b * SEQ + rc * ROWS + row)) * (NH * DV)
                               + h * DV + half * 4);
        *op = o;
    }
}

extern "C" void kernel_launch(void* const* d_in, const int* in_sizes, int n_in,
                              void* d_out, int out_size, void* d_ws, size_t ws_size,
                              hipStream_t stream) {
    const float* x  = (const float*)d_in[0];
    const float* Wq = (const float*)d_in[1];
    const float* Wk = (const float*)d_in[2];
    const float* Wv = (const float*)d_in[3];
    float* out = (float*)d_out;

    const int B = in_sizes[0] / (SEQ * DIN);          // 4
    dim3 grid(B * NH * (SEQ / ROWS));                 // 4*32*16 = 2048
    dim3 block(256);
    hipLaunchKernelGGL(mha_kernel, grid, block, 0, stream, x, Wq, Wk, Wv, out);
}

// Round 3
// 25.564 us; speedup vs baseline: 3.8111x; 1.6323x over previous
//
#include <hip/hip_runtime.h>
#include <hip/hip_bf16.h>
#include <math.h>

#define SEQ  1024
#define NH   32

typedef __attribute__((ext_vector_type(8))) short short8_t;
typedef __attribute__((ext_vector_type(4))) short short4_t;
typedef __attribute__((ext_vector_type(4))) float float4_t;

__device__ inline float exp2_fast(float x) {
#if __has_builtin(__builtin_amdgcn_exp2f)
    return __builtin_amdgcn_exp2f(x);
#else
    return exp2f(x);
#endif
}

__device__ inline short f2bf(float f) {
    __hip_bfloat16 h = __float2bfloat16(f);
    return *reinterpret_cast<short*>(&h);
}

// Block = 512 threads = 8 waves; each wave owns 16 query rows of one (b,h).
// grid = B * NH * (SEQ/128) = 1024 blocks.
//
// scores^T[t,s] = sum_k x[t,k] * y'[s,k]   (K=4 padded to 32, bf16 MFMA)
//   y'[s] = (x_s Wq) Wk^T * (1/sqrt(8)) * log2(e)
// w = exp2(scores)  (no max subtraction needed: |score2| << 127)
// Z^T[c,s] = sum_t XaugT[c,t] * w^T[t,s]   (Xaug cols: x0..x3, ones -> l)
// out[s, h*8+j] = (sum_c Z[c,s] Wv[c,j]) / Z[4,s]
__global__ __launch_bounds__(512, 8) void mha_mfma_kernel(
    const float* __restrict__ x,    // [B, SEQ, 4]
    const float* __restrict__ Wq,   // [NH, 4, 8]
    const float* __restrict__ Wk,   // [NH, 4, 8]
    const float* __restrict__ Wv,   // [NH, 4, 8]
    float* __restrict__ out)        // [B, SEQ, NH*8]
{
    const int bid = blockIdx.x;
    const int rc  = bid & 7;            // row chunk (SEQ/128 = 8)
    const int h   = (bid >> 3) & 31;
    const int b   = bid >> 8;

    const int tid  = threadIdx.x;
    const int lane = tid & 63;
    const int wv   = tid >> 6;
    const int l15  = lane & 15;
    const int g    = lane >> 4;

    __shared__ short xbf[SEQ][4];       // 8 KB   row-major bf16 x
    __shared__ short xT[8][1032];       // 16.5 KB rows: x0..x3, ones, 3x zero (stride 1032 de-banks)

    // ---- stage ----
    const float4* xg = (const float4*)(x + (size_t)b * SEQ * 4);
    for (int i = tid; i < SEQ; i += 512) {
        float4 v = xg[i];
        short s0 = f2bf(v.x), s1 = f2bf(v.y), s2 = f2bf(v.z), s3 = f2bf(v.w);
        short4_t pk = {s0, s1, s2, s3};
        *(short4_t*)(&xbf[i][0]) = pk;
        xT[0][i] = s0; xT[1][i] = s1; xT[2][i] = s2; xT[3][i] = s3;
    }
    for (int i = tid; i < SEQ; i += 512) {
        xT[4][i] = (short)0x3F80;       // 1.0 in bf16 (the l-column)
        xT[5][i] = 0; xT[6][i] = 0; xT[7][i] = 0;
    }

    // ---- per-lane y' (B-frag for the scores MFMA) ----
    const int srow = rc * 128 + wv * 16 + l15;
    const float4 xs = xg[srow];
    const float* wqp = Wq + h * 32;     // [4][8]
    const float* wkp = Wk + h * 32;
    float q[8];
#pragma unroll
    for (int m = 0; m < 8; ++m)
        q[m] = xs.x * wqp[m] + xs.y * wqp[8 + m] + xs.z * wqp[16 + m] + xs.w * wqp[24 + m];
    const float cs = 0.35355339059327373f * 1.4426950408889634f; // 1/sqrt(8)*log2e
    short8_t yfrag = {0, 0, 0, 0, 0, 0, 0, 0};
    if (lane < 16) {
#pragma unroll
        for (int i = 0; i < 4; ++i) {
            float yv = 0.f;
#pragma unroll
            for (int m = 0; m < 8; ++m) yv += q[m] * wkp[i * 8 + m];
            yfrag[i] = f2bf(yv * cs);
        }
    }

    __syncthreads();

    // scores-A: lanes<16 read x rows t0 + f(l15), f = 8*(l>>2)+(l&3); others read zeros
    const short* abase = (lane < 16) ? &xbf[8 * (l15 >> 2) + (l15 & 3)][0] : &xT[5][0];
    const int    astep = (lane < 16) ? 128 : 0;   // 32 rows * 4 shorts per chunk
    // PV-A: xT[c][t0 + 8g .. +7]
    const short* vbase = &xT[l15 & 7][0] + 8 * g;

    float4_t zacc = {0.f, 0.f, 0.f, 0.f};
    const float4_t cz = {0.f, 0.f, 0.f, 0.f};

#pragma unroll 4
    for (int it = 0; it < 32; ++it) {
        short4_t a1lo = *(const short4_t*)abase;          // rows {0..3,8..11,16..19,24..27}+t0
        short4_t a2lo = *(const short4_t*)(abase + 16);   // +4 rows (zeros row if inactive)
        short8_t a1 = {a1lo[0], a1lo[1], a1lo[2], a1lo[3], 0, 0, 0, 0};
        short8_t a2 = {a2lo[0], a2lo[1], a2lo[2], a2lo[3], 0, 0, 0, 0};

        float4_t c1 = __builtin_amdgcn_mfma_f32_16x16x32_bf16(a1, yfrag, cz, 0, 0, 0);
        float4_t c2 = __builtin_amdgcn_mfma_f32_16x16x32_bf16(a2, yfrag, cz, 0, 0, 0);

        short8_t wf;
        wf[0] = f2bf(exp2_fast(c1[0]));
        wf[1] = f2bf(exp2_fast(c1[1]));
        wf[2] = f2bf(exp2_fast(c1[2]));
        wf[3] = f2bf(exp2_fast(c1[3]));
        wf[4] = f2bf(exp2_fast(c2[0]));
        wf[5] = f2bf(exp2_fast(c2[1]));
        wf[6] = f2bf(exp2_fast(c2[2]));
        wf[7] = f2bf(exp2_fast(c2[3]));

        short8_t av = *(const short8_t*)vbase;            // XaugT[c][t0+8g .. +7]
        zacc = __builtin_amdgcn_mfma_f32_16x16x32_bf16(av, wf, zacc, 0, 0, 0);

        abase += astep;
        vbase += 32;
    }

    // ---- epilogue: lane<16 holds Z[0..3][s]; lane 16+s reg0 holds l = Z[4][s] ----
    float lsum = __shfl(zacc[0], 16 + l15);
    float z0 = __shfl(zacc[0], l15);
    float z1 = __shfl(zacc[1], l15);
    float z2 = __shfl(zacc[2], l15);
    float z3 = __shfl(zacc[3], l15);
    if (lane < 32) {
        const float inv = 1.f / lsum;
        const float* wvp = Wv + h * 32 + g * 4;           // half g handles 4 outputs
        float4 o;
        o.x = inv * (z0 * wvp[0] + z1 * wvp[8]  + z2 * wvp[16] + z3 * wvp[24]);
        o.y = inv * (z0 * wvp[1] + z1 * wvp[9]  + z2 * wvp[17] + z3 * wvp[25]);
        o.z = inv * (z0 * wvp[2] + z1 * wvp[10] + z2 * wvp[18] + z3 * wvp[26]);
        o.w = inv * (z0 * wvp[3] + z1 * wvp[11] + z2 * wvp[19] + z3 * wvp[27]);
        float4* op = (float4*)(out + (size_t)(b * SEQ + srow) * (NH * 8) + h * 8 + g * 4);
        *op = o;
    }
}

extern "C" void kernel_launch(void* const* d_in, const int* in_sizes, int n_in,
                              void* d_out, int out_size, void* d_ws, size_t ws_size,
                              hipStream_t stream) {
    const float* x  = (const float*)d_in[0];
    const float* Wq = (const float*)d_in[1];
    const float* Wk = (const float*)d_in[2];
    const float* Wv = (const float*)d_in[3];
    float* out = (float*)d_out;

    const int B = in_sizes[0] / (SEQ * 4);    // 4
    dim3 grid(B * NH * (SEQ / 128));          // 1024
    dim3 block(512);
    hipLaunchKernelGGL(mha_mfma_kernel, grid, block, 0, stream, x, Wq, Wk, Wv, out);
}

// Round 4
// 24.216 us; speedup vs baseline: 4.0232x; 1.0556x over previous
//
#include <hip/hip_runtime.h>
#include <hip/hip_bf16.h>
#include <math.h>

#define SEQ  1024
#define NH   32

typedef __attribute__((ext_vector_type(8))) short short8_t;
typedef __attribute__((ext_vector_type(4))) short short4_t;
typedef __attribute__((ext_vector_type(4))) float float4_t;

__device__ inline float exp2_fast(float x) {
#if __has_builtin(__builtin_amdgcn_exp2f)
    return __builtin_amdgcn_exp2f(x);
#else
    return exp2f(x);
#endif
}

__device__ inline short f2bf(float f) {
    __hip_bfloat16 h = __float2bfloat16(f);
    return *reinterpret_cast<short*>(&h);
}

// Block = 512 threads = 8 waves; each wave owns 32 query rows (two 16-row
// subtiles A/B sharing all LDS reads). grid = B*NH*(SEQ/256) = 512 blocks.
//
// scores^T[t,s] = sum_k x[t,k] * y'[s,k]  (K=4 padded to 32, bf16 MFMA)
//   y'[s] = (x_s Wq) Wk^T * (1/sqrt(8)) * log2(e)
// w = exp2(scores)   (no max subtraction: |score2| << 127, fp32 l can't overflow)
// Z^T[c,s] = sum_t XaugT[c,t] * w^T[t,s]  (Xaug cols: x0..x3, ones -> l)
// out[s, h*8+j] = (sum_c Z[c,s] Wv[c,j]) / Z[4,s]
__global__ __launch_bounds__(512, 4) void mha_mfma_kernel(
    const float* __restrict__ x,    // [B, SEQ, 4]
    const float* __restrict__ Wq,   // [NH, 4, 8]
    const float* __restrict__ Wk,   // [NH, 4, 8]
    const float* __restrict__ Wv,   // [NH, 4, 8]
    float* __restrict__ out)        // [B, SEQ, NH*8]
{
    const int bid = blockIdx.x;
    const int rc  = bid & 3;            // row chunk (SEQ/256 = 4)
    const int h   = (bid >> 2) & 31;
    const int b   = bid >> 7;

    const int tid  = threadIdx.x;
    const int lane = tid & 63;
    const int wv   = tid >> 6;
    const int l15  = lane & 15;
    const int g    = lane >> 4;

    __shared__ short xbf[SEQ][4];       // 8 KB   row-major bf16 x
    __shared__ short xT[8][1032];       // 16.5 KB rows: x0..x3, ones, 3x zero

    // ---- stage ----
    const float4* xg = (const float4*)(x + (size_t)b * SEQ * 4);
    for (int i = tid; i < SEQ; i += 512) {
        float4 v = xg[i];
        short s0 = f2bf(v.x), s1 = f2bf(v.y), s2 = f2bf(v.z), s3 = f2bf(v.w);
        short4_t pk = {s0, s1, s2, s3};
        *(short4_t*)(&xbf[i][0]) = pk;
        xT[0][i] = s0; xT[1][i] = s1; xT[2][i] = s2; xT[3][i] = s3;
        xT[4][i] = (short)0x3F80;       // 1.0 bf16 (l-column)
        xT[5][i] = 0; xT[6][i] = 0; xT[7][i] = 0;
    }

    // ---- per-lane y' for the two subtiles (B-frags of scores MFMA) ----
    const int rowA = rc * 256 + wv * 32 + l15;      // subtile A
    const int rowB = rowA + 16;                     // subtile B
    const float* wqp = Wq + h * 32;     // [4][8]
    const float* wkp = Wk + h * 32;
    const float cs = 0.35355339059327373f * 1.4426950408889634f; // 1/sqrt(8)*log2e
    short8_t yA = {0,0,0,0,0,0,0,0};
    short8_t yB = {0,0,0,0,0,0,0,0};
    if (lane < 16) {
        float4 xsA = xg[rowA];
        float4 xsB = xg[rowB];
#pragma unroll
        for (int i = 0; i < 4; ++i) {
            float ya = 0.f, yb = 0.f;
#pragma unroll
            for (int m = 0; m < 8; ++m) {
                float qa = xsA.x * wqp[m] + xsA.y * wqp[8 + m] + xsA.z * wqp[16 + m] + xsA.w * wqp[24 + m];
                float qb = xsB.x * wqp[m] + xsB.y * wqp[8 + m] + xsB.z * wqp[16 + m] + xsB.w * wqp[24 + m];
                ya += qa * wkp[i * 8 + m];
                yb += qb * wkp[i * 8 + m];
            }
            yA[i] = f2bf(ya * cs);
            yB[i] = f2bf(yb * cs);
        }
    }

    __syncthreads();

    // scores-A: lanes<16 read x rows t0 + f(l15), f = 8*(l>>2)+(l&3); rest read zeros
    const short* abase = (lane < 16) ? &xbf[8 * (l15 >> 2) + (l15 & 3)][0] : &xT[5][0];
    const int    astep = (lane < 16) ? 128 : 0;   // 32 rows * 4 shorts
    // PV-A: xT[c][t0 + 8g .. +7]
    const short* vbase = &xT[l15 & 7][0] + 8 * g;

    float4_t zA = {0.f, 0.f, 0.f, 0.f};
    float4_t zB = {0.f, 0.f, 0.f, 0.f};
    const float4_t cz = {0.f, 0.f, 0.f, 0.f};

#pragma unroll 4
    for (int it = 0; it < 32; ++it) {
        short4_t a1lo = *(const short4_t*)abase;          // rows f(l15)+t0
        short4_t a2lo = *(const short4_t*)(abase + 16);   // +4 rows
        short8_t a1 = {a1lo[0], a1lo[1], a1lo[2], a1lo[3], 0, 0, 0, 0};
        short8_t a2 = {a2lo[0], a2lo[1], a2lo[2], a2lo[3], 0, 0, 0, 0};
        short8_t av = *(const short8_t*)vbase;            // XaugT[c][t0+8g..+7]

        float4_t c1A = __builtin_amdgcn_mfma_f32_16x16x32_bf16(a1, yA, cz, 0, 0, 0);
        float4_t c2A = __builtin_amdgcn_mfma_f32_16x16x32_bf16(a2, yA, cz, 0, 0, 0);
        float4_t c1B = __builtin_amdgcn_mfma_f32_16x16x32_bf16(a1, yB, cz, 0, 0, 0);
        float4_t c2B = __builtin_amdgcn_mfma_f32_16x16x32_bf16(a2, yB, cz, 0, 0, 0);

        short8_t wfA, wfB;
#pragma unroll
        for (int i = 0; i < 4; ++i) {
            wfA[i]     = f2bf(exp2_fast(c1A[i]));
            wfA[4 + i] = f2bf(exp2_fast(c2A[i]));
            wfB[i]     = f2bf(exp2_fast(c1B[i]));
            wfB[4 + i] = f2bf(exp2_fast(c2B[i]));
        }

        zA = __builtin_amdgcn_mfma_f32_16x16x32_bf16(av, wfA, zA, 0, 0, 0);
        zB = __builtin_amdgcn_mfma_f32_16x16x32_bf16(av, wfB, zB, 0, 0, 0);

        abase += astep;
        vbase += 32;
    }

    // ---- epilogue ----
    // C layout: col = lane&15 (s), row = 4*(lane>>4)+reg (c). Need c=0..3 and c=4 (=l).
    float lsA = __shfl(zA[0], 16 + l15);
    float a0  = __shfl(zA[0], l15);
    float a1e = __shfl(zA[1], l15);
    float a2e = __shfl(zA[2], l15);
    float a3e = __shfl(zA[3], l15);
    float lsB = __shfl(zB[0], 16 + l15);
    float b0  = __shfl(zB[0], l15);
    float b1e = __shfl(zB[1], l15);
    float b2e = __shfl(zB[2], l15);
    float b3e = __shfl(zB[3], l15);

    const int  isB  = g >> 1;                 // lanes 32-63 handle subtile B
    const int  half = g & 1;
    const float lsum = isB ? lsB : lsA;
    const float z0 = isB ? b0 : a0;
    const float z1 = isB ? b1e : a1e;
    const float z2 = isB ? b2e : a2e;
    const float z3 = isB ? b3e : a3e;
    const int srow = rowA - l15 + (isB ? 16 : 0) + l15;   // = rowA or rowB for this l15

    const float inv = 1.f / lsum;
    const float* wvp = Wv + h * 32 + half * 4;
    float4 o;
    o.x = inv * (z0 * wvp[0] + z1 * wvp[8]  + z2 * wvp[16] + z3 * wvp[24]);
    o.y = inv * (z0 * wvp[1] + z1 * wvp[9]  + z2 * wvp[17] + z3 * wvp[25]);
    o.z = inv * (z0 * wvp[2] + z1 * wvp[10] + z2 * wvp[18] + z3 * wvp[26]);
    o.w = inv * (z0 * wvp[3] + z1 * wvp[11] + z2 * wvp[19] + z3 * wvp[27]);
    float4* op = (float4*)(out + (size_t)(b * SEQ + srow) * (NH * 8) + h * 8 + half * 4);
    *op = o;
}

extern "C" void kernel_launch(void* const* d_in, const int* in_sizes, int n_in,
                              void* d_out, int out_size, void* d_ws, size_t ws_size,
                              hipStream_t stream) {
    const float* x  = (const float*)d_in[0];
    const float* Wq = (const float*)d_in[1];
    const float* Wk = (const float*)d_in[2];
    const float* Wv = (const float*)d_in[3];
    float* out = (float*)d_out;

    const int B = in_sizes[0] / (SEQ * 4);    // 4
    dim3 grid(B * NH * (SEQ / 256));          // 512
    dim3 block(512);
    hipLaunchKernelGGL(mha_mfma_kernel, grid, block, 0, stream, x, Wq, Wk, Wv, out);
}

// Round 5
// 24.198 us; speedup vs baseline: 4.0262x; 1.0008x over previous
//
#include <hip/hip_runtime.h>
#include <hip/hip_bf16.h>
#include <math.h>

#define SEQ  1024
#define NH   32

typedef __attribute__((ext_vector_type(8))) short short8_t;
typedef __attribute__((ext_vector_type(4))) short short4_t;
typedef __attribute__((ext_vector_type(4))) float float4_t;

__device__ inline float exp2_fast(float x) {
#if __has_builtin(__builtin_amdgcn_exp2f)
    return __builtin_amdgcn_exp2f(x);
#else
    return exp2f(x);
#endif
}

__device__ inline short f2bf(float f) {
    __hip_bfloat16 h = __float2bfloat16(f);
    return *reinterpret_cast<short*>(&h);
}

// Block = 256 threads = 4 waves; each wave owns 32 query rows (two 16-row
// subtiles A/B sharing all LDS reads). grid = B*NH*(SEQ/128) = 1024 blocks.
// 6 blocks/CU -> 24 waves/CU (vs 16 before).
//
// scores^T[t,s] = sum_k x[t,k] * y'[s,k]  (K=4 padded to 32, bf16 MFMA)
//   y'[s] = (x_s Wq) Wk^T * (1/sqrt(8)) * log2(e)
// w = exp2(scores)   (no max subtraction: |score2| << 127, fp32 l can't overflow)
// Z^T[c,s] = sum_t XaugT[c,t] * w^T[t,s]  (Xaug rows: x0..x3, ones -> l, zeros)
// out[s, h*8+j] = (sum_c Z[c,s] Wv[c,j]) / Z[4,s]
//
// Key trick vs round 4: score A-frag reads real x rows on ALL lanes (no zero
// rows, no conditional pointers) — lanes >=16 multiply y'-components that are
// exactly zero, and x is finite, so they contribute nothing.
__global__ __launch_bounds__(256, 6) void mha_mfma_kernel(
    const float* __restrict__ x,    // [B, SEQ, 4]
    const float* __restrict__ Wq,   // [NH, 4, 8]
    const float* __restrict__ Wk,   // [NH, 4, 8]
    const float* __restrict__ Wv,   // [NH, 4, 8]
    float* __restrict__ out)        // [B, SEQ, NH*8]
{
    const int bid = blockIdx.x;
    const int rc  = bid & 7;            // row chunk (SEQ/128 = 8)
    const int h   = (bid >> 3) & 31;
    const int b   = bid >> 8;

    const int tid  = threadIdx.x;
    const int lane = tid & 63;
    const int wv   = tid >> 6;          // 0..3
    const int l15  = lane & 15;
    const int g    = lane >> 4;

    __shared__ short xbf[SEQ][4];       // 8 KB    row-major bf16 x
    __shared__ short xT[6][1032];       // 12.1 KB rows: x0..x3, ones, zeros

    // ---- stage ----
    const float4* xg = (const float4*)(x + (size_t)b * SEQ * 4);
    for (int i = tid; i < SEQ; i += 256) {
        float4 v = xg[i];
        short s0 = f2bf(v.x), s1 = f2bf(v.y), s2 = f2bf(v.z), s3 = f2bf(v.w);
        short4_t pk = {s0, s1, s2, s3};
        *(short4_t*)(&xbf[i][0]) = pk;
        xT[0][i] = s0; xT[1][i] = s1; xT[2][i] = s2; xT[3][i] = s3;
        xT[4][i] = (short)0x3F80;       // 1.0 bf16 (l-column)
        xT[5][i] = 0;                   // zero row (PV A rows >= 5)
    }

    // ---- per-lane y' for the two subtiles (B-frags of scores MFMA) ----
    const int rowA = rc * 128 + wv * 32 + l15;      // subtile A
    const int rowB = rowA + 16;                     // subtile B
    const float* wqp = Wq + h * 32;     // [4][8]
    const float* wkp = Wk + h * 32;
    const float cs = 0.35355339059327373f * 1.4426950408889634f; // 1/sqrt(8)*log2e

    float4 xsA = xg[rowA];
    float4 xsB = xg[rowB];
    float qA[8], qB[8];
#pragma unroll
    for (int m = 0; m < 8; ++m) {
        qA[m] = xsA.x * wqp[m] + xsA.y * wqp[8 + m] + xsA.z * wqp[16 + m] + xsA.w * wqp[24 + m];
        qB[m] = xsB.x * wqp[m] + xsB.y * wqp[8 + m] + xsB.z * wqp[16 + m] + xsB.w * wqp[24 + m];
    }
    short8_t yA = {0,0,0,0,0,0,0,0};
    short8_t yB = {0,0,0,0,0,0,0,0};
    if (lane < 16) {
#pragma unroll
        for (int i = 0; i < 4; ++i) {
            float ya = 0.f, yb = 0.f;
#pragma unroll
            for (int m = 0; m < 8; ++m) {
                ya += qA[m] * wkp[i * 8 + m];
                yb += qB[m] * wkp[i * 8 + m];
            }
            yA[i] = f2bf(ya * cs);
            yB[i] = f2bf(yb * cs);
        }
    }

    __syncthreads();

    // scores-A: ALL lanes read x rows t0 + f(l15), f = 8*(l>>2)+(l&3)
    // (lanes 16..63 duplicate lanes 0..15's addresses -> LDS broadcast, free)
    const short* abase = &xbf[8 * (l15 >> 2) + (l15 & 3)][0];
    // PV-A: row c = l15 (c>=5 -> zero row; their Z rows are ignored)
    const int rowm = (l15 < 5) ? l15 : 5;
    const short* vbase = &xT[rowm][8 * g];

    float4_t zA = {0.f, 0.f, 0.f, 0.f};
    float4_t zB = {0.f, 0.f, 0.f, 0.f};
    const float4_t cz = {0.f, 0.f, 0.f, 0.f};

#pragma unroll 4
    for (int it = 0; it < 32; ++it) {
        short4_t a1lo = *(const short4_t*)(abase + it * 128);        // rows f(l15)+32it
        short4_t a2lo = *(const short4_t*)(abase + it * 128 + 16);   // +4 rows
        short8_t a1 = {a1lo[0], a1lo[1], a1lo[2], a1lo[3], 0, 0, 0, 0};
        short8_t a2 = {a2lo[0], a2lo[1], a2lo[2], a2lo[3], 0, 0, 0, 0};
        short8_t av = *(const short8_t*)(vbase + it * 32);           // XaugT[c][32it+8g..]

        float4_t c1A = __builtin_amdgcn_mfma_f32_16x16x32_bf16(a1, yA, cz, 0, 0, 0);
        float4_t c2A = __builtin_amdgcn_mfma_f32_16x16x32_bf16(a2, yA, cz, 0, 0, 0);
        float4_t c1B = __builtin_amdgcn_mfma_f32_16x16x32_bf16(a1, yB, cz, 0, 0, 0);
        float4_t c2B = __builtin_amdgcn_mfma_f32_16x16x32_bf16(a2, yB, cz, 0, 0, 0);

        short8_t wfA, wfB;
#pragma unroll
        for (int i = 0; i < 4; ++i) {
            wfA[i]     = f2bf(exp2_fast(c1A[i]));
            wfA[4 + i] = f2bf(exp2_fast(c2A[i]));
            wfB[i]     = f2bf(exp2_fast(c1B[i]));
            wfB[4 + i] = f2bf(exp2_fast(c2B[i]));
        }

        zA = __builtin_amdgcn_mfma_f32_16x16x32_bf16(av, wfA, zA, 0, 0, 0);
        zB = __builtin_amdgcn_mfma_f32_16x16x32_bf16(av, wfB, zB, 0, 0, 0);
    }

    // ---- epilogue ----
    // C layout: col = lane&15 (s), row = 4*(lane>>4)+reg (c). Need c=0..3 and c=4 (=l).
    float lsA = __shfl(zA[0], 16 + l15);
    float a0  = __shfl(zA[0], l15);
    float a1e = __shfl(zA[1], l15);
    float a2e = __shfl(zA[2], l15);
    float a3e = __shfl(zA[3], l15);
    float lsB = __shfl(zB[0], 16 + l15);
    float b0  = __shfl(zB[0], l15);
    float b1e = __shfl(zB[1], l15);
    float b2e = __shfl(zB[2], l15);
    float b3e = __shfl(zB[3], l15);

    const int  isB  = g >> 1;                 // lanes 32-63 handle subtile B
    const int  half = g & 1;
    const float lsum = isB ? lsB : lsA;
    const float z0 = isB ? b0 : a0;
    const float z1 = isB ? b1e : a1e;
    const float z2 = isB ? b2e : a2e;
    const float z3 = isB ? b3e : a3e;
    const int srow = rowA + (isB << 4);

    const float inv = 1.f / lsum;
    const float* wvp = Wv + h * 32 + half * 4;
    float4 o;
    o.x = inv * (z0 * wvp[0] + z1 * wvp[8]  + z2 * wvp[16] + z3 * wvp[24]);
    o.y = inv * (z0 * wvp[1] + z1 * wvp[9]  + z2 * wvp[17] + z3 * wvp[25]);
    o.z = inv * (z0 * wvp[2] + z1 * wvp[10] + z2 * wvp[18] + z3 * wvp[26]);
    o.w = inv * (z0 * wvp[3] + z1 * wvp[11] + z2 * wvp[19] + z3 * wvp[27]);
    float4* op = (float4*)(out + (size_t)(b * SEQ + srow) * (NH * 8) + h * 8 + half * 4);
    *op = o;
}

extern "C" void kernel_launch(void* const* d_in, const int* in_sizes, int n_in,
                              void* d_out, int out_size, void* d_ws, size_t ws_size,
                              hipStream_t stream) {
    const float* x  = (const float*)d_in[0];
    const float* Wq = (const float*)d_in[1];
    const float* Wk = (const float*)d_in[2];
    const float* Wv = (const float*)d_in[3];
    float* out = (float*)d_out;

    const int B = in_sizes[0] / (SEQ * 4);    // 4
    dim3 grid(B * NH * (SEQ / 128));          // 1024
    dim3 block(256);
    hipLaunchKernelGGL(mha_mfma_kernel, grid, block, 0, stream, x, Wq, Wk, Wv, out);
}